// Round 1
// baseline (173.004 us; speedup 1.0000x reference)
//
#include <hip/hip_runtime.h>
#include <math.h>

// CAP = (300+400+900)/300/1000*300400 = 1602.13333...; thresh = 0.2*CAP
#define THRESH 320.42666666666668f
#define T_LEN 96
#define DAYS_PER_BLOCK 32   // 256 threads, 8 threads per day

__global__ __launch_bounds__(256) void day_score_kernel(
    const float* __restrict__ pred, const float* __restrict__ tru,
    float* __restrict__ partial, int num_days)
{
    __shared__ float lds_sum;
    if (threadIdx.x == 0) lds_sum = 0.0f;
    __syncthreads();

    const int g   = threadIdx.x >> 3;   // day group within block, 0..31
    const int k   = threadIdx.x & 7;    // thread within day, 0..7
    const int day = blockIdx.x * DAYS_PER_BLOCK + g;

    float s = 0.0f;
    if (day < num_days) {
        const float4* tp = (const float4*)tru  + day * (T_LEN / 4);
        const float4* pp = (const float4*)pred + day * (T_LEN / 4);
#pragma unroll
        for (int m = 0; m < 3; ++m) {
            const float4 tv = tp[k + m * 8];
            const float4 pv = pp[k + m * 8];
            float r;
            r = (tv.x - pv.x) / fmaxf(tv.x, THRESH); s += r * r;
            r = (tv.y - pv.y) / fmaxf(tv.y, THRESH); s += r * r;
            r = (tv.z - pv.z) / fmaxf(tv.z, THRESH); s += r * r;
            r = (tv.w - pv.w) / fmaxf(tv.w, THRESH); s += r * r;
        }
    }
    // reduce across the 8 lanes of this day (groups are 8-lane aligned in the wave)
    s += __shfl_xor(s, 1);
    s += __shfl_xor(s, 2);
    s += __shfl_xor(s, 4);

    if (k == 0 && day < num_days) {
        const float score = (1.0f - sqrtf(s * (1.0f / (float)T_LEN))) * 100.0f;
        atomicAdd(&lds_sum, score);   // LDS atomic, 32 adds/block
    }
    __syncthreads();
    if (threadIdx.x == 0) partial[blockIdx.x] = lds_sum;
}

__global__ __launch_bounds__(256) void final_reduce_kernel(
    const float* __restrict__ partial, int nblocks,
    float* __restrict__ out, float inv_days)
{
    __shared__ float lds[256];
    float s = 0.0f;
    for (int i = threadIdx.x; i < nblocks; i += 256) s += partial[i];
    lds[threadIdx.x] = s;
    __syncthreads();
#pragma unroll
    for (int off = 128; off > 0; off >>= 1) {
        if ((int)threadIdx.x < off) lds[threadIdx.x] += lds[threadIdx.x + off];
        __syncthreads();
    }
    if (threadIdx.x == 0) out[0] = lds[0] * inv_days;
}

extern "C" void kernel_launch(void* const* d_in, const int* in_sizes, int n_in,
                              void* d_out, int out_size, void* d_ws, size_t ws_size,
                              hipStream_t stream) {
    (void)n_in; (void)out_size; (void)ws_size;
    const float* pred = (const float*)d_in[0];   // setup_inputs: {"pred": ..., "true": ...}
    const float* tru  = (const float*)d_in[1];
    float* out = (float*)d_out;
    float* partial = (float*)d_ws;

    const int n        = in_sizes[1];
    const int num_days = n / T_LEN;
    const int nblocks  = (num_days + DAYS_PER_BLOCK - 1) / DAYS_PER_BLOCK;

    day_score_kernel<<<nblocks, 256, 0, stream>>>(pred, tru, partial, num_days);
    final_reduce_kernel<<<1, 256, 0, stream>>>(partial, nblocks, out,
                                               1.0f / (float)num_days);
}

// Round 2
// 170.794 us; speedup vs baseline: 1.0129x; 1.0129x over previous
//
#include <hip/hip_runtime.h>
#include <math.h>

// CAP = (300+400+900)/300/1000*300400 = 1602.13333...; thresh = 0.2*CAP
#define THRESH 320.42666666666668f
#define T_LEN 96
#define TPD 4               // threads per day
#define DAYS_PER_BLOCK 64   // 256 threads / 4 per day

__global__ __launch_bounds__(256) void day_score_kernel(
    const float* __restrict__ pred, const float* __restrict__ tru,
    float* __restrict__ partial, int num_days)
{
    __shared__ float lds_sum;
    if (threadIdx.x == 0) lds_sum = 0.0f;
    __syncthreads();

    const int g   = threadIdx.x >> 2;   // day group within block, 0..63
    const int k   = threadIdx.x & 3;    // thread within day, 0..3
    const int day = blockIdx.x * DAYS_PER_BLOCK + g;

    float s = 0.0f;
    if (day < num_days) {
        const float4* tp = (const float4*)tru  + day * (T_LEN / 4);
        const float4* pp = (const float4*)pred + day * (T_LEN / 4);

        // Phase 1: issue ALL loads before any compute (12 loads in flight)
        float4 tv[6], pv[6];
#pragma unroll
        for (int j = 0; j < 6; ++j) tv[j] = tp[k + j * TPD];
#pragma unroll
        for (int j = 0; j < 6; ++j) pv[j] = pp[k + j * TPD];

        // Phase 2: compute. denom >= 320 so fast rcp is safe (~1e-6 rel err).
#pragma unroll
        for (int j = 0; j < 6; ++j) {
            float r;
            r = (tv[j].x - pv[j].x) * __builtin_amdgcn_rcpf(fmaxf(tv[j].x, THRESH)); s += r * r;
            r = (tv[j].y - pv[j].y) * __builtin_amdgcn_rcpf(fmaxf(tv[j].y, THRESH)); s += r * r;
            r = (tv[j].z - pv[j].z) * __builtin_amdgcn_rcpf(fmaxf(tv[j].z, THRESH)); s += r * r;
            r = (tv[j].w - pv[j].w) * __builtin_amdgcn_rcpf(fmaxf(tv[j].w, THRESH)); s += r * r;
        }
    }
    // reduce across the 4 lanes of this day (groups are 4-lane aligned in the wave)
    s += __shfl_xor(s, 1);
    s += __shfl_xor(s, 2);

    if (k == 0 && day < num_days) {
        const float score = (1.0f - sqrtf(s * (1.0f / (float)T_LEN))) * 100.0f;
        atomicAdd(&lds_sum, score);   // LDS atomic, 64 adds/block
    }
    __syncthreads();
    if (threadIdx.x == 0) partial[blockIdx.x] = lds_sum;
}

__global__ __launch_bounds__(256) void final_reduce_kernel(
    const float* __restrict__ partial, int nblocks,
    float* __restrict__ out, float inv_days)
{
    __shared__ float lds[256];
    float s = 0.0f;
    for (int i = threadIdx.x; i < nblocks; i += 256) s += partial[i];
    lds[threadIdx.x] = s;
    __syncthreads();
#pragma unroll
    for (int off = 128; off > 0; off >>= 1) {
        if ((int)threadIdx.x < off) lds[threadIdx.x] += lds[threadIdx.x + off];
        __syncthreads();
    }
    if (threadIdx.x == 0) out[0] = lds[0] * inv_days;
}

extern "C" void kernel_launch(void* const* d_in, const int* in_sizes, int n_in,
                              void* d_out, int out_size, void* d_ws, size_t ws_size,
                              hipStream_t stream) {
    (void)n_in; (void)out_size; (void)ws_size;
    const float* pred = (const float*)d_in[0];   // setup_inputs: {"pred": ..., "true": ...}
    const float* tru  = (const float*)d_in[1];
    float* out = (float*)d_out;
    float* partial = (float*)d_ws;

    const int n        = in_sizes[1];
    const int num_days = n / T_LEN;
    const int nblocks  = (num_days + DAYS_PER_BLOCK - 1) / DAYS_PER_BLOCK;

    day_score_kernel<<<nblocks, 256, 0, stream>>>(pred, tru, partial, num_days);
    final_reduce_kernel<<<1, 256, 0, stream>>>(partial, nblocks, out,
                                               1.0f / (float)num_days);
}

// Round 3
// 170.139 us; speedup vs baseline: 1.0168x; 1.0039x over previous
//
#include <hip/hip_runtime.h>
#include <math.h>

// CAP = (300+400+900)/300/1000*300400 = 1602.13333...; thresh = 0.2*CAP
#define THRESH 320.42666666666668f
#define T_LEN 96
#define DPB 64                              // days per block
#define F4_PER_BLOCK (DPB * T_LEN / 4)      // 1536 float4 per input per block
#define LDS_ROW 25                          // 24 + 1 pad -> conflict-free reads

__global__ __launch_bounds__(256) void day_score_kernel(
    const float* __restrict__ pred, const float* __restrict__ tru,
    float* __restrict__ out, int num_days, float inv_days)
{
    __shared__ float sf[DPB * LDS_ROW];     // 6.25 KB transpose buffer
    const int t = threadIdx.x;
    const long long base = (long long)blockIdx.x * F4_PER_BLOCK;
    const float4* tp = (const float4*)tru  + base;
    const float4* pp = (const float4*)pred + base;

    const int total_f4 = (num_days * T_LEN) / 4;
    const bool full = (base + F4_PER_BLOCK) <= total_f4;

    // ---- Phase 1: issue ALL 12 loads (contiguous 1 KB per wave-load) ----
    float4 tv[6], pv[6];
    if (full) {
#pragma unroll
        for (int j = 0; j < 6; ++j) tv[j] = tp[t + j * 256];
#pragma unroll
        for (int j = 0; j < 6; ++j) pv[j] = pp[t + j * 256];
    } else {
        const float4 z = make_float4(0.f, 0.f, 0.f, 0.f);
#pragma unroll
        for (int j = 0; j < 6; ++j) {
            const bool ok = (base + t + j * 256) < total_f4;
            tv[j] = ok ? tp[t + j * 256] : z;
            pv[j] = ok ? pp[t + j * 256] : z;
        }
    }
    __builtin_amdgcn_sched_barrier(0);      // compiler may NOT sink loads past here

    // ---- Phase 2: per-float4 partial sums -> LDS transpose ----
#pragma unroll
    for (int j = 0; j < 6; ++j) {
        float r, s4;
        r = (tv[j].x - pv[j].x) * __builtin_amdgcn_rcpf(fmaxf(tv[j].x, THRESH)); s4  = r * r;
        r = (tv[j].y - pv[j].y) * __builtin_amdgcn_rcpf(fmaxf(tv[j].y, THRESH)); s4 += r * r;
        r = (tv[j].z - pv[j].z) * __builtin_amdgcn_rcpf(fmaxf(tv[j].z, THRESH)); s4 += r * r;
        r = (tv[j].w - pv[j].w) * __builtin_amdgcn_rcpf(fmaxf(tv[j].w, THRESH)); s4 += r * r;
        const int f = t + j * 256;          // local float4 index; never crosses a day (96/4=24)
        sf[(f / 24) * LDS_ROW + (f % 24)] = s4;
    }
    __syncthreads();

    // ---- Phase 3: wave 0 (lanes 0..63) owns one day each ----
    if (t < DPB) {
        float s = 0.f;
#pragma unroll
        for (int m = 0; m < 24; ++m) s += sf[t * LDS_ROW + m];
        const int day = blockIdx.x * DPB + t;
        float score = (day < num_days)
                        ? (1.0f - sqrtf(s * (1.0f / (float)T_LEN))) * 100.0f
                        : 0.0f;
        // full-wave butterfly (threads 0..63 are exactly wave 0)
        score += __shfl_xor(score, 1);
        score += __shfl_xor(score, 2);
        score += __shfl_xor(score, 4);
        score += __shfl_xor(score, 8);
        score += __shfl_xor(score, 16);
        score += __shfl_xor(score, 32);
        if (t == 0) atomicAdd(out, score * inv_days);
    }
}

extern "C" void kernel_launch(void* const* d_in, const int* in_sizes, int n_in,
                              void* d_out, int out_size, void* d_ws, size_t ws_size,
                              hipStream_t stream) {
    (void)n_in; (void)d_ws; (void)ws_size;
    const float* pred = (const float*)d_in[0];   // setup_inputs: {"pred": ..., "true": ...}
    const float* tru  = (const float*)d_in[1];
    float* out = (float*)d_out;

    const int n        = in_sizes[1];
    const int num_days = n / T_LEN;
    const int nblocks  = (num_days + DPB - 1) / DPB;

    hipMemsetAsync(out, 0, (size_t)out_size * sizeof(float), stream);
    day_score_kernel<<<nblocks, 256, 0, stream>>>(pred, tru, out, num_days,
                                                  1.0f / (float)num_days);
}